// Round 7
// baseline (203.673 us; speedup 1.0000x reference)
//
#include <hip/hip_runtime.h>
#include <hip/hip_bf16.h>
#include <stdint.h>

// Problem constants (from reference setup_inputs)
#define BB 64
#define SS 2048
#define DD 6
#define HH 8
#define NCH 512           // chains = B*H
#define CHUNKS 256        // chunks per chain
#define LCH 8             // steps per chunk = SS/CHUNKS
// WORKSPACE CEILING: 80 MB. Rounds 1/4 (80 MB) were replay-stable; round 6
// (96 MB) passed first check then diverged on replays -> OOB stomp. Do not grow.

typedef unsigned short ushort_t;
typedef __attribute__((ext_vector_type(8))) __bf16 bf16x8;
typedef __attribute__((ext_vector_type(4))) float f32x4;

// ---------------- compile-time Cayley sign table (Cl(4,1)) ----------------
struct SignTab { float s[32][32]; };

constexpr int popc5_c(unsigned v) {
    int c = 0;
    for (int i = 0; i < 5; ++i) c += (v >> i) & 1u;
    return c;
}

constexpr SignTab make_signs() {
    SignTab t{};
    for (int a = 0; a < 32; ++a) {
        for (int b = 0; b < 32; ++b) {
            int cnt = 0;
            unsigned aa = ((unsigned)a) >> 1;
            while (aa) { cnt += popc5_c(aa & (unsigned)b); aa >>= 1; }
            if ((a & b) & 16) cnt += 1;   // metric: e5^2 = -1 (bit 4)
            t.s[a][b] = (cnt & 1) ? -1.0f : 1.0f;
        }
    }
    return t;
}

constexpr SignTab SGN = make_signs();

// out = a * b  (geometric product, a is LEFT operand: out_k = sum_i s(i,i^k) a_i b_{i^k})
__device__ __forceinline__ void gp_cl41(const float* __restrict__ a,
                                        const float* __restrict__ b,
                                        float* __restrict__ o) {
#pragma unroll
    for (int k = 0; k < 32; ++k) o[k] = 0.0f;
#pragma unroll
    for (int i = 0; i < 32; ++i) {
#pragma unroll
        for (int k = 0; k < 32; ++k) {
            o[k] = fmaf(SGN.s[i][i ^ k] * a[i], b[i ^ k], o[k]);
        }
    }
}

__device__ __forceinline__ float sumsq32(const float* v) {
    float n0 = 0.f, n1 = 0.f, n2 = 0.f, n3 = 0.f;
#pragma unroll
    for (int k = 0; k < 32; k += 4) {
        n0 = fmaf(v[k+0], v[k+0], n0);
        n1 = fmaf(v[k+1], v[k+1], n1);
        n2 = fmaf(v[k+2], v[k+2], n2);
        n3 = fmaf(v[k+3], v[k+3], n3);
    }
    return (n0 + n1) + (n2 + n3);
}

__device__ __forceinline__ float rsq(float n) {
    return __builtin_amdgcn_rsqf(n);   // v_rsq_f32, scale-equivalent
}

__device__ __forceinline__ uint32_t f2bf_rne(float f) {
    uint32_t u = __float_as_uint(f);
    return (u + 0x7FFFu + ((u >> 16) & 1u)) >> 16;
}

// fp16 pack/unpack (RNE); only LEAF data (psi_loc) is fp16 — each element feeds
// exactly one GP, so quantization does not compound. SCAN-PATH data (Tbuf/Ebuf)
// stays fp32: carry = product of up to 256 totals -> per-total quantization
// accumulates as sqrt(n)*eps (fp16 gave 0.036 absmax in round 5).
__device__ __forceinline__ uint32_t packh2(float a, float b) {
    union { _Float16 h[2]; uint32_t u; } t;
    t.h[0] = (_Float16)a; t.h[1] = (_Float16)b;
    return t.u;
}
__device__ __forceinline__ float h2lo(uint32_t u) {
    union { uint32_t u32; _Float16 h[2]; } t; t.u32 = u; return (float)t.h[0];
}
__device__ __forceinline__ float h2hi(uint32_t u) {
    union { uint32_t u32; _Float16 h[2]; } t; t.u32 = u; return (float)t.h[1];
}

__device__ __forceinline__ void pack_store16(ushort_t* dst, const float* v, float scale) {
    uint32_t pk[16];
#pragma unroll
    for (int m = 0; m < 16; ++m)
        pk[m] = packh2(v[2*m] * scale, v[2*m+1] * scale);
    uint4* d4 = (uint4*)dst;
#pragma unroll
    for (int m = 0; m < 4; ++m)
        d4[m] = make_uint4(pk[4*m], pk[4*m+1], pk[4*m+2], pk[4*m+3]);
}

__device__ __forceinline__ void load_unpack16(const ushort_t* src, float* v) {
    const uint4* s4 = (const uint4*)src;
#pragma unroll
    for (int m = 0; m < 4; ++m) {
        uint4 t4 = s4[m];
        uint32_t uu[4] = { t4.x, t4.y, t4.z, t4.w };
#pragma unroll
        for (int z = 0; z < 4; ++z) {
            v[8*m + 2*z]     = h2lo(uu[z]);
            v[8*m + 2*z + 1] = h2hi(uu[z]);
        }
    }
}

// ---------------- K1: fused delta-compute + chunk-local prefix ----------------
// 131072 threads (2048 waves = 2/SIMD), 8 sequential GP steps per thread.
// Chain UNNORMALIZED (positive-rescale equivalence); fp32-safe range.
// x for pair pr+1 is prefetched before pair pr's GPs (VMEM hidden under compute).
__global__ __launch_bounds__(256) void k_local(
        const float* __restrict__ x, const float* __restrict__ W_in,
        const float* __restrict__ b_in, ushort_t* __restrict__ psi_loc,
        float* __restrict__ Tbuf) {
    __shared__ float4 sW4[8][57];   // [h][d*8+j4] = W, [h][48..55] = bias
    for (int idx = threadIdx.x; idx < 8 * 56; idx += 256) {
        int h = idx / 56, r = idx % 56;
        float4 v;
        if (r < 48) {
            int d = r / 8, j4 = r % 8;
            const float* p = W_in + d * 256 + h * 32 + 4 * j4;
            v = make_float4(p[0], p[1], p[2], p[3]);
        } else {
            const float* p = b_in + h * 32 + 4 * (r - 48);
            v = make_float4(p[0], p[1], p[2], p[3]);
        }
        sW4[h][r] = v;
    }
    __syncthreads();

    int tid = blockIdx.x * 256 + threadIdx.x;
    int c  = tid >> 9;                 // 0..255
    int bh = tid & 511;
    int b = bh >> 3, h = bh & 7;

    float4 bias4[8];
#pragma unroll
    for (int j4 = 0; j4 < 8; ++j4) bias4[j4] = sW4[h][48 + j4];

    float p[32];
#pragma unroll
    for (int k = 0; k < 32; ++k) p[k] = 0.f;
    p[0] = 1.f;

    const float* xrow = x + ((size_t)b * SS + (size_t)c * LCH) * DD;  // 48 floats, 16B-aligned
    ushort_t* psi_base = psi_loc + (((size_t)b * SS + (size_t)c * LCH) * HH + h) * 32;

    // prefetch pair 0 (12 floats = 3 float4)
    float xc[12];
    {
        const float4* xp = (const float4*)xrow;
#pragma unroll
        for (int m = 0; m < 3; ++m) {
            float4 t4 = xp[m];
            xc[4*m+0] = t4.x; xc[4*m+1] = t4.y; xc[4*m+2] = t4.z; xc[4*m+3] = t4.w;
        }
    }

#pragma unroll 1
    for (int pr = 0; pr < LCH / 2; ++pr) {
        float x0[6], x1[6];
#pragma unroll
        for (int d = 0; d < 6; ++d) { x0[d] = xc[d]; x1[d] = xc[6 + d]; }

        // prefetch next pair while this pair computes
        if (pr < LCH / 2 - 1) {
            const float4* xp = (const float4*)(xrow + (pr + 1) * 12);
#pragma unroll
            for (int m = 0; m < 3; ++m) {
                float4 t4 = xp[m];
                xc[4*m+0] = t4.x; xc[4*m+1] = t4.y; xc[4*m+2] = t4.z; xc[4*m+3] = t4.w;
            }
        }

        float dl0[32], dl1[32];
#pragma unroll
        for (int j4 = 0; j4 < 8; ++j4) {
            float4 bv = bias4[j4];
            dl0[4*j4+0] = bv.x; dl0[4*j4+1] = bv.y; dl0[4*j4+2] = bv.z; dl0[4*j4+3] = bv.w;
            dl1[4*j4+0] = bv.x; dl1[4*j4+1] = bv.y; dl1[4*j4+2] = bv.z; dl1[4*j4+3] = bv.w;
        }
#pragma unroll
        for (int d = 0; d < 6; ++d) {
            float a0 = x0[d], a1 = x1[d];
#pragma unroll
            for (int j4 = 0; j4 < 8; ++j4) {
                float4 w = sW4[h][d * 8 + j4];   // one LDS read serves both steps
                dl0[4*j4+0] = fmaf(a0, w.x, dl0[4*j4+0]);
                dl0[4*j4+1] = fmaf(a0, w.y, dl0[4*j4+1]);
                dl0[4*j4+2] = fmaf(a0, w.z, dl0[4*j4+2]);
                dl0[4*j4+3] = fmaf(a0, w.w, dl0[4*j4+3]);
                dl1[4*j4+0] = fmaf(a1, w.x, dl1[4*j4+0]);
                dl1[4*j4+1] = fmaf(a1, w.y, dl1[4*j4+1]);
                dl1[4*j4+2] = fmaf(a1, w.z, dl1[4*j4+2]);
                dl1[4*j4+3] = fmaf(a1, w.w, dl1[4*j4+3]);
            }
        }
        dl0[0] += 1.0f;
        dl1[0] += 1.0f;

        float o[32];
        gp_cl41(dl0, p, o);   // newer delta LEFT; chain unnormalized
        pack_store16(psi_base + (size_t)(2 * pr) * HH * 32, o, rsq(sumsq32(o)));
        gp_cl41(dl1, o, p);
        pack_store16(psi_base + (size_t)(2 * pr + 1) * HH * 32, p, rsq(sumsq32(p)));
    }

    // normalized chunk total, fp32 (scan-path precision)
    float inv = rsq(sumsq32(p));
    float* dst = Tbuf + ((size_t)bh * CHUNKS + c) * 32;
#pragma unroll
    for (int k = 0; k < 32; ++k) dst[k] = p[k] * inv;
}

// ---------------- K2: work-efficient pair + Kogge-Stone scan per chain ----------------
// 256 chunks -> 128 pairs; 1 GP (pair) + 7 KS rounds + 1 GP (odd fixup) = 9 GPs
// per thread, 128 threads per chain (vs 8 GPs x 256 threads in round 4: 44% less work,
// one fewer round, 2-wave barriers). Ebuf aliases Tbuf: each thread writes ONLY the
// slots it itself read (t0/t1 held in registers), so no cross-thread hazard.
__global__ __launch_bounds__(128) void k_scan_totals(
        const float* __restrict__ Tbuf, float* __restrict__ Ebuf) {
    __shared__ float sT[128][33];      // +1 pad
    int chain = blockIdx.x;            // 0..511
    int pp = threadIdx.x;              // pair index 0..127

    // load T[2p], T[2p+1] (256 B contiguous fp32); keep t0 in registers to the end
    float t0[32], t1[32];
    {
        const float* s0 = Tbuf + ((size_t)chain * CHUNKS + 2 * pp) * 32;
#pragma unroll
        for (int k = 0; k < 32; ++k) t0[k] = s0[k];
#pragma unroll
        for (int k = 0; k < 32; ++k) t1[k] = s0[32 + k];
    }

    float v[32];
    {
        float o[32];
        gp_cl41(t1, t0, o);            // pair total: newer (2p+1) LEFT
        float inv = rsq(sumsq32(o));
#pragma unroll
        for (int k = 0; k < 32; ++k) { v[k] = o[k] * inv; sT[pp][k] = v[k]; }
    }
    __syncthreads();

#pragma unroll 1
    for (int off = 1; off < 128; off <<= 1) {
        float w[32];
        bool act = (pp >= off);
        if (act) {
#pragma unroll
            for (int k = 0; k < 32; ++k) w[k] = sT[pp - off][k];
        }
        __syncthreads();
        if (act) {
            float o[32];
            gp_cl41(v, w, o);          // v covers newer range -> left
            float inv = rsq(sumsq32(o));
#pragma unroll
            for (int k = 0; k < 32; ++k) { v[k] = o[k] * inv; sT[pp][k] = v[k]; }
        }
        __syncthreads();
    }

    // exclusive carries at chunk granularity:
    // E[2p]   = I[p-1]   (pairs p-1..0 = chunks 2p-1..0);  E[0] = identity
    // E[2p+1] = T[2p] * I[p-1]
    float e0[32];
    if (pp == 0) {
#pragma unroll
        for (int k = 0; k < 32; ++k) e0[k] = (k == 0) ? 1.f : 0.f;
    } else {
#pragma unroll
        for (int k = 0; k < 32; ++k) e0[k] = sT[pp - 1][k];
    }
    float e1[32];
    gp_cl41(t0, e0, e1);               // T[2p] (newer) LEFT
    float inv1 = rsq(sumsq32(e1));

    float* d0 = Ebuf + ((size_t)chain * CHUNKS + 2 * pp) * 32;
#pragma unroll
    for (int k = 0; k < 32; ++k) d0[k] = e0[k];
#pragma unroll
    for (int k = 0; k < 32; ++k) d0[32 + k] = e1[k] * inv1;
}

// ---------------- K3: fused fixup (GP with carry) + MFMA projection + norm ----------------
// One wave per 16-row tile, 2048 blocks (no tile loop).
__global__ __launch_bounds__(256) void k_fixup_proj(
        const ushort_t* __restrict__ psi_loc, const float* __restrict__ Ebuf,
        const float* __restrict__ W_out, const float* __restrict__ b_out,
        float* __restrict__ out) {
    int lane = threadIdx.x & 63;
    int wv = threadIdx.x >> 6;
    int q = lane >> 4;          // quad id 0..3
    int n0 = lane & 15;         // output column within 16-tile

    // B-fragments in registers: B[k][n], k = kk*32 + q*8 + j, n = nt*16 + n0
    bf16x8 Bf[2][8];
#pragma unroll
    for (int nt = 0; nt < 2; ++nt)
#pragma unroll
        for (int kk = 0; kk < 8; ++kk) {
            union { ushort_t u[8]; bf16x8 v; } tmp;
#pragma unroll
            for (int j = 0; j < 8; ++j)
                tmp.u[j] = (ushort_t)f2bf_rne(W_out[(kk * 32 + q * 8 + j) * 32 + nt * 16 + n0]);
            Bf[nt][kk] = tmp.v;
        }
    float bn0 = b_out[n0], bn1 = b_out[16 + n0];

    __shared__ ushort_t psiT[4][16][264];   // 16 rows x 256 bf16 (+8 pad) per wave

    int tile = blockIdx.x * 4 + wv;         // 0..8191
    int rr0 = tile * 16;
    int b = rr0 >> 11;                      // 16-row tiles never straddle b
    int s0 = rr0 & 2047;

    // fixup: 128 (row,h) pairs -> 2 per lane
#pragma unroll
    for (int pp = 0; pp < 2; ++pp) {
        int row_local = pp * 8 + (lane >> 3);
        int h = lane & 7;
        int s = s0 + row_local;
        int c = s >> 3;                     // LCH=8
        int bh = b * 8 + h;

        float a[32], w[32], o[32];
        load_unpack16(psi_loc + (((size_t)b * SS + s) * HH + h) * 32, a);
        const float* e = Ebuf + ((size_t)bh * CHUNKS + c) * 32;
#pragma unroll
        for (int k = 0; k < 32; ++k) w[k] = e[k];

        gp_cl41(a, w, o);                   // local (newer) LEFT x carry
        float inv = rsq(sumsq32(o));

        uint32_t pk[16];
#pragma unroll
        for (int m = 0; m < 16; ++m)
            pk[m] = f2bf_rne(o[2*m] * inv) | (f2bf_rne(o[2*m+1] * inv) << 16);
        uint4* dst = (uint4*)&psiT[wv][row_local][h * 32];
#pragma unroll
        for (int m = 0; m < 4; ++m)
            dst[m] = make_uint4(pk[4*m], pk[4*m+1], pk[4*m+2], pk[4*m+3]);
    }

    __syncthreads();

    // projection: 16x256 @ 256x32 via 16 MFMAs
    f32x4 acc0 = {0.f, 0.f, 0.f, 0.f};
    f32x4 acc1 = {0.f, 0.f, 0.f, 0.f};
#pragma unroll
    for (int kk = 0; kk < 8; ++kk) {
        // A-frag: A[m=lane&15][k=kk*32+q*8+j]
        bf16x8 af = *(const bf16x8*)&psiT[wv][n0][kk * 32 + q * 8];
        acc0 = __builtin_amdgcn_mfma_f32_16x16x32_bf16(af, Bf[0][kk], acc0, 0, 0, 0);
        acc1 = __builtin_amdgcn_mfma_f32_16x16x32_bf16(af, Bf[1][kk], acc1, 0, 0, 0);
    }

    // epilogue: bias, row-norm across 32 cols (16 lanes x 2), store
    float c0[4], c1[4], ss[4];
#pragma unroll
    for (int i = 0; i < 4; ++i) {
        c0[i] = acc0[i] + bn0;
        c1[i] = acc1[i] + bn1;
        ss[i] = c0[i] * c0[i] + c1[i] * c1[i];
    }
#pragma unroll
    for (int m = 1; m < 16; m <<= 1) {
#pragma unroll
        for (int i = 0; i < 4; ++i) ss[i] += __shfl_xor(ss[i], m);
    }
#pragma unroll
    for (int i = 0; i < 4; ++i) {
        float inv = rsq(ss[i]);
        int row = rr0 + q * 4 + i;
        out[(size_t)row * 32 + n0]      = c0[i] * inv;
        out[(size_t)row * 32 + 16 + n0] = c1[i] * inv;
    }
}

// ---------------- launcher ----------------
extern "C" void kernel_launch(void* const* d_in, const int* in_sizes, int n_in,
                              void* d_out, int out_size, void* d_ws, size_t ws_size,
                              hipStream_t stream) {
    const float* x     = (const float*)d_in[0];
    const float* W_in  = (const float*)d_in[1];
    const float* b_in  = (const float*)d_in[2];
    const float* W_out = (const float*)d_in[3];
    const float* b_out = (const float*)d_in[4];
    float* out = (float*)d_out;

    char* ws = (char*)d_ws;
    ushort_t* psi  = (ushort_t*)ws;                              // 64 MB fp16 local prefixes
    float* Tbuf = (float*)(ws + (size_t)64 * 1024 * 1024);       // 512*256*32*4 = 16 MB fp32
    float* Ebuf = Tbuf;                                          // aliased (safe, see K2)
    // total: exactly 80 MB (proven-safe ceiling)

    k_local      <<< 512, 256, 0, stream>>>(x, W_in, b_in, psi, Tbuf);
    k_scan_totals<<< 512, 128, 0, stream>>>(Tbuf, Ebuf);
    k_fixup_proj <<<2048, 256, 0, stream>>>(psi, Ebuf, W_out, b_out, out);
}